// Round 7
// baseline (270.102 us; speedup 1.0000x reference)
//
#include <hip/hip_runtime.h>
#include <hip/hip_bf16.h>
#include <hip/hip_fp16.h>

// Problem constants
#define B_  2
#define N_  1024
#define D_  256
#define E_  64
#define H_  8
#define HS_ 64
#define FF_ 1024
#define R_  (B_*N_)   // 2048 rows (b,n)

typedef short bf8 __attribute__((ext_vector_type(8)));   // 8 bf16 (bit pattern) = 4 VGPRs
typedef float f4  __attribute__((ext_vector_type(4)));

static __device__ __forceinline__ ushort f2b(float f) {
  __hip_bfloat16 h = __float2bfloat16(f);
  return *reinterpret_cast<ushort*>(&h);
}

static __device__ __forceinline__ ushort4 f4_to_b4(float4 v) {
  ushort4 r;
  r.x = f2b(v.x); r.y = f2b(v.y); r.z = f2b(v.z); r.w = f2b(v.w);
  return r;
}

// ---------------- fused weight pack (all bf16, B-matrices TRANSPOSED [N][K]) ----------------
__global__ void k_pack(const float* __restrict__ node, const float* __restrict__ Wq,
                       const float* __restrict__ Wk, const float* __restrict__ Wv,
                       const float* __restrict__ Wp, const float* __restrict__ W1,
                       const float* __restrict__ W2,
                       ushort* __restrict__ node_bf, ushort* __restrict__ wqkvT,
                       ushort* __restrict__ wkeT, ushort* __restrict__ wpT,
                       ushort* __restrict__ w1T, ushort* __restrict__ w2T) {
  int idx = blockIdx.x * 256 + threadIdx.x;
  if (idx < 524288) {                       // node -> bf16
    node_bf[idx] = f2b(node[idx]);
    return;
  }
  idx -= 524288;
  if (idx < 393216) {                       // wqkvT[c][i], c in [0,1536), K=256
    int c = idx >> 8, i = idx & 255;
    int mat = c >> 9, h = (c >> 6) & 7, o = c & 63;
    float v;
    if (mat == 0)      v = Wq[(h * 256 + i) * 64 + o] * 0.125f;   // q scaled 1/sqrt(HS)
    else if (mat == 1) v = Wk[(h * 320 + i) * 64 + o];            // Wk: [H][320][64]
    else               v = Wv[(h * 256 + i) * 64 + o];
    wqkvT[idx] = f2b(v);
    return;
  }
  idx -= 393216;
  if (idx < 262144) {                       // wkeT[c=h2*64+e][r=h*64+o]  (block-diagonal)
    int c = idx >> 9, r = idx & 511;
    int h2 = c >> 6, e = c & 63, h = r >> 6, o = r & 63;
    wkeT[idx] = (h2 == h) ? f2b(Wk[(h * 320 + 256 + e) * 64 + o]) : (ushort)0;
    return;
  }
  idx -= 262144;
  if (idx < 131072) {                       // wpT[c][r], c in [0,256), r = h*64+i
    int c = idx >> 9, r = idx & 511;
    wpT[idx] = f2b(Wp[r * 256 + c]);
    return;
  }
  idx -= 131072;
  if (idx < 262144) {                       // w1T[c][k], c in [0,1024), K=256
    int c = idx >> 8, k = idx & 255;
    w1T[idx] = f2b(W1[k * 1024 + c]);
    return;
  }
  idx -= 262144;
  {                                         // w2T[c][k], c in [0,256), K=1024
    int c = idx >> 10, k = idx & 1023;
    w2T[idx] = f2b(W2[k * 256 + c]);
  }
}

// vT[b][h][o][m] <- qkv[(b*1024+m)*1536 + 1024 + h*64 + o]   (B^T panel for attn@v)
__global__ void k_vT(const ushort* __restrict__ qkv, ushort* __restrict__ vt) {
  int idx = blockIdx.x * 256 + threadIdx.x;   // 16*64*1024
  if (idx >= 16 * 64 * 1024) return;
  int m = idx & 1023;
  int rest = idx >> 10;
  int o = rest & 63;
  int bh = rest >> 6;
  int b = bh >> 3, h = bh & 7;
  vt[idx] = qkv[(size_t)(b * 1024 + m) * 1536 + 1024 + h * 64 + o];
}

// ---------------- generic bf16 MFMA GEMM, B pre-transposed ----------------
// C[M x N] = A[M x K] @ B[K x N];  Bt is B^T, row-major [N][K] with stride ldbt.
// EPI: 0=none, 2=+bias, 3=+bias,relu   OFMT: 0=f32, 1=bf16, 2=f16
// NBT: 64-col tiles per block (block = 64 x 64*NBT)
// BDIAG: B block-diagonal with 64x64 blocks -> K-loop restricted to [c0, c0+64)
// Batched via blockIdx.z: offset = (z>>3)*s1 + (z&7)*s2  (element offsets)
template<int EPI, int OFMT, int NBT, bool BDIAG>
__global__ void k_gemm(const ushort* __restrict__ A, const ushort* __restrict__ Bt,
                       void* __restrict__ Cv, const float* __restrict__ bias,
                       int M, int N, int K, int lda, int ldbt, int ldc,
                       long long as1, long long as2, long long bs1, long long bs2,
                       long long cs1, long long cs2) {
  int z = blockIdx.z;
  const ushort* Ab = A  + (size_t)((z >> 3) * as1 + (z & 7) * as2);
  const ushort* Bb = Bt + (size_t)((z >> 3) * bs1 + (z & 7) * bs2);
  size_t coff = (size_t)((z >> 3) * cs1 + (z & 7) * cs2);
  int r0 = blockIdx.x * 64, c0 = blockIdx.y * (64 * NBT);

  __shared__ ushort As[64][40];          // [row][k], +8 pad
  __shared__ ushort Bs[64 * NBT][40];    // [col][k], +8 pad

  int tid = threadIdx.x;
  int lane = tid & 63, w = tid >> 6;
  int wm = w >> 1, wn = w & 1;            // wave -> 32-row half x 32-col half
  int kg = lane >> 4, lr = lane & 15;

  f4 acc[2][2 * NBT] = {};

  int kbeg = BDIAG ? c0 : 0;
  int kend = BDIAG ? c0 + 64 : K;
  for (int k0 = kbeg; k0 < kend; k0 += 32) {
    __syncthreads();
    { // stage A tile 64x32 (one 16B load per thread)
      int row = tid >> 2, ch = tid & 3;
      *(int4*)&As[row][ch * 8] = *(const int4*)(Ab + (size_t)(r0 + row) * lda + k0 + ch * 8);
    }
    #pragma unroll
    for (int i = 0; i < NBT; ++i) { // stage Bt tile 64*NBT x 32
      int row = (tid >> 2) + 64 * i, ch = tid & 3;
      *(int4*)&Bs[row][ch * 8] = *(const int4*)(Bb + (size_t)(c0 + row) * ldbt + k0 + ch * 8);
    }
    __syncthreads();

    bf8 bfr[2 * NBT];
    #pragma unroll
    for (int nt = 0; nt < NBT; ++nt)
      #pragma unroll
      for (int cb = 0; cb < 2; ++cb)
        bfr[nt * 2 + cb] = *(const bf8*)&Bs[nt * 64 + wn * 32 + cb * 16 + lr][kg * 8];
    #pragma unroll
    for (int rb = 0; rb < 2; ++rb) {
      bf8 af = *(const bf8*)&As[wm * 32 + rb * 16 + lr][kg * 8];     // A: row=l&15, k=8*kg+j
      #pragma unroll
      for (int q = 0; q < 2 * NBT; ++q)
        acc[rb][q] = __builtin_amdgcn_mfma_f32_16x16x32_bf16(af, bfr[q], acc[rb][q], 0, 0, 0);
    }
  }

  float*  Cf = (float*)Cv;
  ushort* Cb = (ushort*)Cv;
  __half* Ch = (__half*)Cv;
  #pragma unroll
  for (int rb = 0; rb < 2; ++rb) {
    #pragma unroll
    for (int q = 0; q < 2 * NBT; ++q) {
      #pragma unroll
      for (int rr = 0; rr < 4; ++rr) {
        int row = r0 + wm * 32 + rb * 16 + kg * 4 + rr;   // D: col=l&15, row=4*kg+reg
        int col = c0 + (q >> 1) * 64 + wn * 32 + (q & 1) * 16 + lr;
        size_t ci = coff + (size_t)row * ldc + col;
        float v = acc[rb][q][rr];
        if (EPI >= 2) v += bias[col];
        if (EPI == 3) v = fmaxf(v, 0.0f);
        if (OFMT == 1)      Cb[ci] = f2b(v);
        else if (OFMT == 2) Ch[ci] = __float2half(v);
        else                Cf[ci] = v;
      }
    }
  }
}

// ---------------- GEMM + bias + residual + LayerNorm (16-row x 256-col blocks) ----------------
// C = LN(A @ Bt^T + bias + resid); grid = M/16 = 128 blocks; wave owns 16 rows x 64 cols
// (acc[4] = 16 VGPRs). Row reduce: 16-lane shfl_xor + 4-wave LDS combine.
__global__ __launch_bounds__(256) void k_gemm_ln(
    const ushort* __restrict__ A, const ushort* __restrict__ Bt,
    const float* __restrict__ bias, const float* __restrict__ resid,
    const float* __restrict__ g, const float* __restrict__ be,
    float* __restrict__ of, ushort* __restrict__ ob, int K) {
  int r0 = blockIdx.x * 16;
  __shared__ ushort As[16][40];
  __shared__ ushort Bs[256][40];
  __shared__ float redL[2][4][16];   // [sum|var][wave][row]
  int tid = threadIdx.x, lane = tid & 63, w = tid >> 6;
  int kg = lane >> 4, lr = lane & 15;

  f4 acc[4] = {};
  for (int k0 = 0; k0 < K; k0 += 32) {
    __syncthreads();
    if (tid < 64) {                   // stage A 16x32
      int row = tid >> 2, ch = tid & 3;
      *(int4*)&As[row][ch * 8] = *(const int4*)(A + (size_t)(r0 + row) * K + k0 + ch * 8);
    }
    #pragma unroll
    for (int j = 0; j < 4; ++j) {     // stage Bt 256x32
      int pos = tid + 256 * j, row = pos >> 2, ch = pos & 3;
      *(int4*)&Bs[row][ch * 8] = *(const int4*)(Bt + (size_t)row * K + k0 + ch * 8);
    }
    __syncthreads();
    bf8 af = *(const bf8*)&As[lr][kg * 8];           // A: row=l&15, k=8*kg+j
    #pragma unroll
    for (int fc = 0; fc < 4; ++fc) {
      bf8 bf = *(const bf8*)&Bs[w * 64 + fc * 16 + lr][kg * 8];
      acc[fc] = __builtin_amdgcn_mfma_f32_16x16x32_bf16(af, bf, acc[fc], 0, 0, 0);
    }
  }

  // bias + residual (fp32)
  #pragma unroll
  for (int fc = 0; fc < 4; ++fc) {
    int col = w * 64 + fc * 16 + lr;
    #pragma unroll
    for (int rr = 0; rr < 4; ++rr) {
      int row = r0 + kg * 4 + rr;
      acc[fc][rr] += bias[col] + resid[(size_t)row * 256 + col];
    }
  }
  // row sums: 16-lane shfl within wave's 64-col slice, then 4-wave combine
  float s[4];
  #pragma unroll
  for (int rr = 0; rr < 4; ++rr) {
    float v = acc[0][rr] + acc[1][rr] + acc[2][rr] + acc[3][rr];
    #pragma unroll
    for (int off = 1; off < 16; off <<= 1) v += __shfl_xor(v, off);
    s[rr] = v;
  }
  if (lr == 0) {
    #pragma unroll
    for (int rr = 0; rr < 4; ++rr) redL[0][w][kg * 4 + rr] = s[rr];
  }
  __syncthreads();
  float mean[4];
  #pragma unroll
  for (int rr = 0; rr < 4; ++rr) {
    int row = kg * 4 + rr;
    mean[rr] = (redL[0][0][row] + redL[0][1][row] + redL[0][2][row] + redL[0][3][row])
               * (1.0f / 256.0f);
  }
  #pragma unroll
  for (int rr = 0; rr < 4; ++rr) {
    float v = 0.f;
    #pragma unroll
    for (int fc = 0; fc < 4; ++fc) { float d = acc[fc][rr] - mean[rr]; v += d * d; }
    #pragma unroll
    for (int off = 1; off < 16; off <<= 1) v += __shfl_xor(v, off);
    s[rr] = v;
  }
  if (lr == 0) {
    #pragma unroll
    for (int rr = 0; rr < 4; ++rr) redL[1][w][kg * 4 + rr] = s[rr];
  }
  __syncthreads();
  float rstd[4];
  #pragma unroll
  for (int rr = 0; rr < 4; ++rr) {
    int row = kg * 4 + rr;
    rstd[rr] = rsqrtf((redL[1][0][row] + redL[1][1][row] + redL[1][2][row] + redL[1][3][row])
                      * (1.0f / 256.0f) + 1e-6f);
  }
  #pragma unroll
  for (int fc = 0; fc < 4; ++fc) {
    int col = w * 64 + fc * 16 + lr;
    float gg = g[col], bb = be[col];
    #pragma unroll
    for (int rr = 0; rr < 4; ++rr) {
      int row = r0 + kg * 4 + rr;
      float y = (acc[fc][rr] - mean[rr]) * rstd[rr] * gg + bb;
      of[(size_t)row * 256 + col] = y;
      if (ob) ob[(size_t)row * 256 + col] = f2b(y);
    }
  }
}

// ---------------- fused edge-logits (MFMA) + node-logits + softmax -> bf16 attn ----------------
__global__ __launch_bounds__(256, 4) void k_fused(
    const float* __restrict__ edge, const float* __restrict__ qe,
    const __half* __restrict__ logN, ushort* __restrict__ attn) {
  int bid = blockIdx.x;            // b*1024 + n
  int b = bid >> 10, n = bid & 1023;
  int t = threadIdx.x;
  int lane = t & 63, w = t >> 6;
  int kg = lane >> 4, lr = lane & 15;

  __shared__ ushort As[128 * 64];  // 16 KB bf16 stage, slot^(row&7) swizzle
  __shared__ __half lg[1024 * 9];  // block logits [m][h], pad-9, fp16 (18 KB)
  __shared__ float red[2][4][8];

  // ---- B fragments (qe row -> bf16), built once, kept in 8 VGPRs ----
  bf8 bq[2];
  {
    const float* qrow = qe + (size_t)bid * 512 + (size_t)(lr & 7) * 64;
    #pragma unroll
    for (int kk = 0; kk < 2; ++kk) {
      float4 a  = *reinterpret_cast<const float4*>(&qrow[kk * 32 + kg * 8]);
      float4 c4 = *reinterpret_cast<const float4*>(&qrow[kk * 32 + kg * 8 + 4]);
      bq[kk][0] = (short)f2b(a.x);  bq[kk][1] = (short)f2b(a.y);
      bq[kk][2] = (short)f2b(a.z);  bq[kk][3] = (short)f2b(a.w);
      bq[kk][4] = (short)f2b(c4.x); bq[kk][5] = (short)f2b(c4.y);
      bq[kk][6] = (short)f2b(c4.z); bq[kk][7] = (short)f2b(c4.w);
    }
  }

  const float* eb = edge + (size_t)bid * 65536;   // 1024 rows x 64 floats

  // prefetch tile 0 (8 float4/thread, fully coalesced)
  float4 pf[8];
  #pragma unroll
  for (int u = 0; u < 8; ++u)
    pf[u] = reinterpret_cast<const float4*>(eb)[t + 256 * u];

  #pragma unroll 1
  for (int tl = 0; tl < 8; ++tl) {
    __syncthreads();               // prev tile's A-frag reads done
    #pragma unroll
    for (int u = 0; u < 8; ++u) {  // cvt fp32->bf16, swizzled write: slot ^= row&7
      int g = t + 256 * u;
      int rl = g >> 4, c = t & 15;          // row 0..127, float4-slot 0..15
      int slot = (c >> 1) ^ (rl & 7), half = c & 1;
      *reinterpret_cast<ushort4*>(&As[rl * 64 + slot * 8 + half * 4]) = f4_to_b4(pf[u]);
    }
    if (tl < 7) {                  // issue next tile's loads; hide under compute
      const float4* src = reinterpret_cast<const float4*>(eb + (tl + 1) * 8192);
      #pragma unroll
      for (int u = 0; u < 8; ++u) pf[u] = src[t + 256 * u];
    }
    __syncthreads();               // stage visible

    // wave w owns stage rows [w*32, w*32+32): 2 sub-tiles of 16 m
    #pragma unroll
    for (int sub = 0; sub < 2; ++sub) {
      int sr = w * 32 + sub * 16 + lr;      // A row in stage
      f4 acc = {};
      #pragma unroll
      for (int kk = 0; kk < 2; ++kk) {
        bf8 af = *reinterpret_cast<const bf8*>(&As[sr * 64 + (((kk * 4 + kg) ^ (sr & 7)) << 3)]);
        acc = __builtin_amdgcn_mfma_f32_16x16x32_bf16(af, bq[kk], acc, 0, 0, 0);
      }
      if (lr < 8) {                         // D: col=l&15 (=h), row=4*kg+rr
        int mbase = tl * 128 + w * 32 + sub * 16 + kg * 4;
        #pragma unroll
        for (int rr = 0; rr < 4; ++rr)
          lg[(mbase + rr) * 9 + lr] = __float2half(acc[rr]);
      }
    }
  }

  // issue node-logit loads BEFORE the barrier: they overlap the lg drain
  ushort lNr[4][8];
  #pragma unroll
  for (int j = 0; j < 4; ++j)
    #pragma unroll
    for (int h = 0; h < 8; ++h)
      lNr[j][h] = *reinterpret_cast<const ushort*>(
          &logN[((size_t)(b * 8 + h) * 1024 + n) * 1024 + t + 256 * j]);
  __syncthreads();                 // lg complete

  // ---- softmax: thread owns m = t + 256j ----
  float l[4][8];
  #pragma unroll
  for (int j = 0; j < 4; ++j) {
    int m = t + 256 * j;
    #pragma unroll
    for (int h = 0; h < 8; ++h)
      l[j][h] = __half2float(lg[m * 9 + h]) +
                __half2float(*reinterpret_cast<const __half*>(&lNr[j][h]));
  }
  float mx[8], sm[8];
  #pragma unroll
  for (int h = 0; h < 8; ++h) {
    float v = fmaxf(fmaxf(l[0][h], l[1][h]), fmaxf(l[2][h], l[3][h]));
    #pragma unroll
    for (int off = 32; off; off >>= 1) v = fmaxf(v, __shfl_xor(v, off));
    if (lane == 0) red[0][w][h] = v;
  }
  __syncthreads();
  #pragma unroll
  for (int h = 0; h < 8; ++h)
    mx[h] = fmaxf(fmaxf(red[0][0][h], red[0][1][h]), fmaxf(red[0][2][h], red[0][3][h]));
  #pragma unroll
  for (int j = 0; j < 4; ++j)
    #pragma unroll
    for (int h = 0; h < 8; ++h)
      l[j][h] = __expf(l[j][h] - mx[h]);
  #pragma unroll
  for (int h = 0; h < 8; ++h) {
    float v = l[0][h] + l[1][h] + l[2][h] + l[3][h];
    #pragma unroll
    for (int off = 32; off; off >>= 1) v += __shfl_xor(v, off);
    if (lane == 0) red[1][w][h] = v;
  }
  __syncthreads();
  #pragma unroll
  for (int h = 0; h < 8; ++h)
    sm[h] = 1.0f / (red[1][0][h] + red[1][1][h] + red[1][2][h] + red[1][3][h]);
  #pragma unroll
  for (int h = 0; h < 8; ++h) {
    size_t base = ((size_t)(b * 8 + h) * 1024 + n) * 1024;
    #pragma unroll
    for (int j = 0; j < 4; ++j)
      attn[base + t + 256 * j] = f2b(l[j][h] * sm[h]);
  }
}

// ---------------- launch ----------------

extern "C" void kernel_launch(void* const* d_in, const int* in_sizes, int n_in,
                              void* d_out, int out_size, void* d_ws, size_t ws_size,
                              hipStream_t stream) {
  (void)in_sizes; (void)n_in; (void)out_size; (void)ws_size;
  const float* node = (const float*)d_in[0];
  const float* edge = (const float*)d_in[1];
  const float* Wq   = (const float*)d_in[2];
  const float* Wk   = (const float*)d_in[3];
  const float* Wv   = (const float*)d_in[4];
  const float* Wp   = (const float*)d_in[5];
  const float* bp   = (const float*)d_in[6];
  const float* g1   = (const float*)d_in[7];
  const float* be1  = (const float*)d_in[8];
  const float* W1   = (const float*)d_in[9];
  const float* b1   = (const float*)d_in[10];
  const float* W2   = (const float*)d_in[11];
  const float* b2   = (const float*)d_in[12];
  const float* g2   = (const float*)d_in[13];
  const float* be2  = (const float*)d_in[14];
  float* out = (float*)d_out;

  char* ws = (char*)d_ws;
  size_t off = 0;
  auto alloc = [&](size_t bytes) -> char* {
    char* p = ws + off;
    off = (off + bytes + 255) & ~(size_t)255;
    return p;
  };
  ushort* node_bf = (ushort*)alloc((size_t)R_ * D_ * 2);
  ushort* wqkvT   = (ushort*)alloc((size_t)1536 * 256 * 2);
  ushort* wkeT    = (ushort*)alloc((size_t)512 * 512 * 2);
  ushort* wpT     = (ushort*)alloc((size_t)256 * 512 * 2);
  ushort* w1T     = (ushort*)alloc((size_t)1024 * 256 * 2);
  ushort* w2T     = (ushort*)alloc((size_t)256 * 1024 * 2);
  ushort* qkv     = (ushort*)alloc((size_t)R_ * 1536 * 2);        // 6 MiB
  float*  qe      = (float*) alloc((size_t)R_ * 512 * 4);         // 4 MiB
  ushort* vt      = (ushort*)alloc((size_t)16 * 64 * 1024 * 2);   // 2 MiB
  __half* logits  = (__half*)alloc((size_t)16 * 1024 * 1024 * 2); // 32 MiB fp16
  ushort* attn    = (ushort*)alloc((size_t)16 * 1024 * 1024 * 2); // 32 MiB
  ushort* mo      = (ushort*)alloc((size_t)R_ * 512 * 2);
  float*  xf      = (float*) alloc((size_t)R_ * 256 * 4);
  ushort* xb      = (ushort*)alloc((size_t)R_ * 256 * 2);
  ushort* hb      = (ushort*)alloc((size_t)R_ * 1024 * 2);

  // --- single fused pack ---
  k_pack<<<dim3(7168), dim3(256), 0, stream>>>(node, Wq, Wk, Wv, Wp, W1, W2,
                                               node_bf, wqkvT, wkeT, wpT, w1T, w2T);

  // --- qkv = node @ Wqkv (bf16 out, q pre-scaled) ---
  k_gemm<0, 1, 1, false><<<dim3(32, 24, 1), dim3(256), 0, stream>>>(
      node_bf, wqkvT, qkv, nullptr, 2048, 1536, 256, 256, 256, 1536,
      0LL, 0LL, 0LL, 0LL, 0LL, 0LL);

  // --- qe = q @ blockdiag(WkE^T)  (fp32 out; BDIAG skips the zero K-blocks) ---
  k_gemm<0, 0, 1, true><<<dim3(32, 8, 1), dim3(256), 0, stream>>>(
      qkv, wkeT, qe, nullptr, 2048, 512, 512, 1536, 512, 512,
      0LL, 0LL, 0LL, 0LL, 0LL, 0LL);

  // --- vT pack (for attn@v B-panel) ---
  k_vT<<<dim3(4096), dim3(256), 0, stream>>>(qkv, vt);

  // --- node logits = q @ kn^T  (batched over (b,h); 64x256 tiles; fp16 out) ---
  k_gemm<0, 2, 4, false><<<dim3(16, 4, 16), dim3(256), 0, stream>>>(
      qkv, qkv + 512, logits, nullptr, 1024, 1024, 64, 1536, 1536, 1024,
      1572864LL, 64LL, 1572864LL, 64LL, 8388608LL, 1048576LL);

  // --- fused: edge MFMA dot + node logits + softmax -> bf16 attn ---
  k_fused<<<dim3(2048), dim3(256), 0, stream>>>(edge, qe, logits, attn);

  // --- mo = attn @ v  (batched; Bt = vT; bf16 out as [b][n][h*64+o]) ---
  k_gemm<0, 1, 1, false><<<dim3(16, 1, 16), dim3(256), 0, stream>>>(
      attn, vt, mo, nullptr, 1024, 64, 1024, 1024, 1024, 512,
      8388608LL, 1048576LL, 524288LL, 65536LL, 524288LL, 64LL);

  // --- x = LN1(mo @ Wp + bp + node) -> xf (fp32), xb (bf16)  [fused GEMM+LN, 128 blocks] ---
  k_gemm_ln<<<dim3(128), dim3(256), 0, stream>>>(
      mo, wpT, bp, node, g1, be1, xf, xb, 512);

  // --- ffn hidden = relu(x @ W1 + b1)  (bf16) ---
  k_gemm<3, 1, 1, false><<<dim3(32, 16, 1), dim3(256), 0, stream>>>(
      xb, w1T, hb, b1, 2048, 1024, 256, 256, 256, 1024,
      0LL, 0LL, 0LL, 0LL, 0LL, 0LL);

  // --- out = LN2(hidden @ W2 + b2 + x)  (fp32 to d_out)  [fused GEMM+LN, 128 blocks] ---
  k_gemm_ln<<<dim3(128), dim3(256), 0, stream>>>(
      hb, w2T, b2, xf, g2, be2, out, nullptr, 1024);
}

// Round 8
// 226.788 us; speedup vs baseline: 1.1910x; 1.1910x over previous
//
#include <hip/hip_runtime.h>
#include <hip/hip_bf16.h>
#include <hip/hip_fp16.h>

// Problem constants
#define B_  2
#define N_  1024
#define D_  256
#define E_  64
#define H_  8
#define HS_ 64
#define FF_ 1024
#define R_  (B_*N_)   // 2048 rows (b,n)

typedef short bf8 __attribute__((ext_vector_type(8)));   // 8 bf16 (bit pattern) = 4 VGPRs
typedef float f4  __attribute__((ext_vector_type(4)));

static __device__ __forceinline__ ushort f2b(float f) {
  __hip_bfloat16 h = __float2bfloat16(f);
  return *reinterpret_cast<ushort*>(&h);
}

static __device__ __forceinline__ ushort4 f4_to_b4(float4 v) {
  ushort4 r;
  r.x = f2b(v.x); r.y = f2b(v.y); r.z = f2b(v.z); r.w = f2b(v.w);
  return r;
}

// ---------------- fused weight pack (all bf16, B-matrices TRANSPOSED [N][K]) ----------------
__global__ void k_pack(const float* __restrict__ node, const float* __restrict__ Wq,
                       const float* __restrict__ Wk, const float* __restrict__ Wv,
                       const float* __restrict__ Wp, const float* __restrict__ W1,
                       const float* __restrict__ W2,
                       ushort* __restrict__ node_bf, ushort* __restrict__ wqkvT,
                       ushort* __restrict__ wkeT, ushort* __restrict__ wpT,
                       ushort* __restrict__ w1T, ushort* __restrict__ w2T) {
  int idx = blockIdx.x * 256 + threadIdx.x;
  if (idx < 524288) {                       // node -> bf16
    node_bf[idx] = f2b(node[idx]);
    return;
  }
  idx -= 524288;
  if (idx < 393216) {                       // wqkvT[c][i], c in [0,1536), K=256
    int c = idx >> 8, i = idx & 255;
    int mat = c >> 9, h = (c >> 6) & 7, o = c & 63;
    float v;
    if (mat == 0)      v = Wq[(h * 256 + i) * 64 + o] * 0.125f;   // q scaled 1/sqrt(HS)
    else if (mat == 1) v = Wk[(h * 320 + i) * 64 + o];            // Wk: [H][320][64]
    else               v = Wv[(h * 256 + i) * 64 + o];
    wqkvT[idx] = f2b(v);
    return;
  }
  idx -= 393216;
  if (idx < 262144) {                       // wkeT[c=h2*64+e][r=h*64+o]  (block-diagonal)
    int c = idx >> 9, r = idx & 511;
    int h2 = c >> 6, e = c & 63, h = r >> 6, o = r & 63;
    wkeT[idx] = (h2 == h) ? f2b(Wk[(h * 320 + 256 + e) * 64 + o]) : (ushort)0;
    return;
  }
  idx -= 262144;
  if (idx < 131072) {                       // wpT[c][r], c in [0,256), r = h*64+i
    int c = idx >> 9, r = idx & 511;
    wpT[idx] = f2b(Wp[r * 256 + c]);
    return;
  }
  idx -= 131072;
  if (idx < 262144) {                       // w1T[c][k], c in [0,1024), K=256
    int c = idx >> 8, k = idx & 255;
    w1T[idx] = f2b(W1[k * 1024 + c]);
    return;
  }
  idx -= 262144;
  {                                         // w2T[c][k], c in [0,256), K=1024
    int c = idx >> 10, k = idx & 1023;
    w2T[idx] = f2b(W2[k * 256 + c]);
  }
}

// vT[b][h][o][m] <- qkv[(b*1024+m)*1536 + 1024 + h*64 + o]   (B^T panel for attn@v)
__global__ void k_vT(const ushort* __restrict__ qkv, ushort* __restrict__ vt) {
  int idx = blockIdx.x * 256 + threadIdx.x;   // 16*64*1024
  if (idx >= 16 * 64 * 1024) return;
  int m = idx & 1023;
  int rest = idx >> 10;
  int o = rest & 63;
  int bh = rest >> 6;
  int b = bh >> 3, h = bh & 7;
  vt[idx] = qkv[(size_t)(b * 1024 + m) * 1536 + 1024 + h * 64 + o];
}

// ---------------- generic bf16 MFMA GEMM, B pre-transposed ----------------
// C[M x N] = A[M x K] @ B[K x N];  Bt is B^T, row-major [N][K] with stride ldbt.
// EPI: 0=none, 2=+bias, 3=+bias,relu   OFMT: 0=f32, 1=bf16, 2=f16
// NBT: 64-col tiles per block (block = 64 x 64*NBT)
// BDIAG: B block-diagonal with 64x64 blocks -> K-loop restricted to [c0, c0+64)
// Batched via blockIdx.z: offset = (z>>3)*s1 + (z&7)*s2  (element offsets)
template<int EPI, int OFMT, int NBT, bool BDIAG>
__global__ void k_gemm(const ushort* __restrict__ A, const ushort* __restrict__ Bt,
                       void* __restrict__ Cv, const float* __restrict__ bias,
                       int M, int N, int K, int lda, int ldbt, int ldc,
                       long long as1, long long as2, long long bs1, long long bs2,
                       long long cs1, long long cs2) {
  int z = blockIdx.z;
  const ushort* Ab = A  + (size_t)((z >> 3) * as1 + (z & 7) * as2);
  const ushort* Bb = Bt + (size_t)((z >> 3) * bs1 + (z & 7) * bs2);
  size_t coff = (size_t)((z >> 3) * cs1 + (z & 7) * cs2);
  int r0 = blockIdx.x * 64, c0 = blockIdx.y * (64 * NBT);

  __shared__ ushort As[64][40];          // [row][k], +8 pad
  __shared__ ushort Bs[64 * NBT][40];    // [col][k], +8 pad

  int tid = threadIdx.x;
  int lane = tid & 63, w = tid >> 6;
  int wm = w >> 1, wn = w & 1;            // wave -> 32-row half x 32-col half
  int kg = lane >> 4, lr = lane & 15;

  f4 acc[2][2 * NBT] = {};

  int kbeg = BDIAG ? c0 : 0;
  int kend = BDIAG ? c0 + 64 : K;
  for (int k0 = kbeg; k0 < kend; k0 += 32) {
    __syncthreads();
    { // stage A tile 64x32 (one 16B load per thread)
      int row = tid >> 2, ch = tid & 3;
      *(int4*)&As[row][ch * 8] = *(const int4*)(Ab + (size_t)(r0 + row) * lda + k0 + ch * 8);
    }
    #pragma unroll
    for (int i = 0; i < NBT; ++i) { // stage Bt tile 64*NBT x 32
      int row = (tid >> 2) + 64 * i, ch = tid & 3;
      *(int4*)&Bs[row][ch * 8] = *(const int4*)(Bb + (size_t)(c0 + row) * ldbt + k0 + ch * 8);
    }
    __syncthreads();

    bf8 bfr[2 * NBT];
    #pragma unroll
    for (int nt = 0; nt < NBT; ++nt)
      #pragma unroll
      for (int cb = 0; cb < 2; ++cb)
        bfr[nt * 2 + cb] = *(const bf8*)&Bs[nt * 64 + wn * 32 + cb * 16 + lr][kg * 8];
    #pragma unroll
    for (int rb = 0; rb < 2; ++rb) {
      bf8 af = *(const bf8*)&As[wm * 32 + rb * 16 + lr][kg * 8];     // A: row=l&15, k=8*kg+j
      #pragma unroll
      for (int q = 0; q < 2 * NBT; ++q)
        acc[rb][q] = __builtin_amdgcn_mfma_f32_16x16x32_bf16(af, bfr[q], acc[rb][q], 0, 0, 0);
    }
  }

  float*  Cf = (float*)Cv;
  ushort* Cb = (ushort*)Cv;
  __half* Ch = (__half*)Cv;
  #pragma unroll
  for (int rb = 0; rb < 2; ++rb) {
    #pragma unroll
    for (int q = 0; q < 2 * NBT; ++q) {
      #pragma unroll
      for (int rr = 0; rr < 4; ++rr) {
        int row = r0 + wm * 32 + rb * 16 + kg * 4 + rr;   // D: col=l&15, row=4*kg+reg
        int col = c0 + (q >> 1) * 64 + wn * 32 + (q & 1) * 16 + lr;
        size_t ci = coff + (size_t)row * ldc + col;
        float v = acc[rb][q][rr];
        if (EPI >= 2) v += bias[col];
        if (EPI == 3) v = fmaxf(v, 0.0f);
        if (OFMT == 1)      Cb[ci] = f2b(v);
        else if (OFMT == 2) Ch[ci] = __float2half(v);
        else                Cf[ci] = v;
      }
    }
  }
}

// ---------------- fused edge-logits (MFMA) + node-logits + softmax -> bf16 attn ----------------
__global__ __launch_bounds__(256, 4) void k_fused(
    const float* __restrict__ edge, const float* __restrict__ qe,
    const __half* __restrict__ logN, ushort* __restrict__ attn) {
  int bid = blockIdx.x;            // b*1024 + n
  int b = bid >> 10, n = bid & 1023;
  int t = threadIdx.x;
  int lane = t & 63, w = t >> 6;
  int kg = lane >> 4, lr = lane & 15;

  __shared__ ushort As[128 * 64];  // 16 KB bf16 stage, slot^(row&7) swizzle
  __shared__ __half lg[1024 * 9];  // block logits [m][h], pad-9, fp16 (18 KB)
  __shared__ float red[2][4][8];

  // ---- B fragments (qe row -> bf16), built once, kept in 8 VGPRs ----
  bf8 bq[2];
  {
    const float* qrow = qe + (size_t)bid * 512 + (size_t)(lr & 7) * 64;
    #pragma unroll
    for (int kk = 0; kk < 2; ++kk) {
      float4 a  = *reinterpret_cast<const float4*>(&qrow[kk * 32 + kg * 8]);
      float4 c4 = *reinterpret_cast<const float4*>(&qrow[kk * 32 + kg * 8 + 4]);
      bq[kk][0] = (short)f2b(a.x);  bq[kk][1] = (short)f2b(a.y);
      bq[kk][2] = (short)f2b(a.z);  bq[kk][3] = (short)f2b(a.w);
      bq[kk][4] = (short)f2b(c4.x); bq[kk][5] = (short)f2b(c4.y);
      bq[kk][6] = (short)f2b(c4.z); bq[kk][7] = (short)f2b(c4.w);
    }
  }

  const float* eb = edge + (size_t)bid * 65536;   // 1024 rows x 64 floats

  // prefetch tile 0 (8 float4/thread, fully coalesced)
  float4 pf[8];
  #pragma unroll
  for (int u = 0; u < 8; ++u)
    pf[u] = reinterpret_cast<const float4*>(eb)[t + 256 * u];

  #pragma unroll 1
  for (int tl = 0; tl < 8; ++tl) {
    __syncthreads();               // prev tile's A-frag reads done
    #pragma unroll
    for (int u = 0; u < 8; ++u) {  // cvt fp32->bf16, swizzled write: slot ^= row&7
      int g = t + 256 * u;
      int rl = g >> 4, c = t & 15;          // row 0..127, float4-slot 0..15
      int slot = (c >> 1) ^ (rl & 7), half = c & 1;
      *reinterpret_cast<ushort4*>(&As[rl * 64 + slot * 8 + half * 4]) = f4_to_b4(pf[u]);
    }
    if (tl < 7) {                  // issue next tile's loads; hide under compute
      const float4* src = reinterpret_cast<const float4*>(eb + (tl + 1) * 8192);
      #pragma unroll
      for (int u = 0; u < 8; ++u) pf[u] = src[t + 256 * u];
    }
    __syncthreads();               // stage visible

    // wave w owns stage rows [w*32, w*32+32): 2 sub-tiles of 16 m
    #pragma unroll
    for (int sub = 0; sub < 2; ++sub) {
      int sr = w * 32 + sub * 16 + lr;      // A row in stage
      f4 acc = {};
      #pragma unroll
      for (int kk = 0; kk < 2; ++kk) {
        bf8 af = *reinterpret_cast<const bf8*>(&As[sr * 64 + (((kk * 4 + kg) ^ (sr & 7)) << 3)]);
        acc = __builtin_amdgcn_mfma_f32_16x16x32_bf16(af, bq[kk], acc, 0, 0, 0);
      }
      if (lr < 8) {                         // D: col=l&15 (=h), row=4*kg+rr
        int mbase = tl * 128 + w * 32 + sub * 16 + kg * 4;
        #pragma unroll
        for (int rr = 0; rr < 4; ++rr)
          lg[(mbase + rr) * 9 + lr] = __float2half(acc[rr]);
      }
    }
  }

  // issue node-logit loads BEFORE the barrier: they overlap the lg drain
  ushort lNr[4][8];
  #pragma unroll
  for (int j = 0; j < 4; ++j)
    #pragma unroll
    for (int h = 0; h < 8; ++h)
      lNr[j][h] = *reinterpret_cast<const ushort*>(
          &logN[((size_t)(b * 8 + h) * 1024 + n) * 1024 + t + 256 * j]);
  __syncthreads();                 // lg complete

  // ---- softmax: thread owns m = t + 256j ----
  float l[4][8];
  #pragma unroll
  for (int j = 0; j < 4; ++j) {
    int m = t + 256 * j;
    #pragma unroll
    for (int h = 0; h < 8; ++h)
      l[j][h] = __half2float(lg[m * 9 + h]) +
                __half2float(*reinterpret_cast<const __half*>(&lNr[j][h]));
  }
  float mx[8], sm[8];
  #pragma unroll
  for (int h = 0; h < 8; ++h) {
    float v = fmaxf(fmaxf(l[0][h], l[1][h]), fmaxf(l[2][h], l[3][h]));
    #pragma unroll
    for (int off = 32; off; off >>= 1) v = fmaxf(v, __shfl_xor(v, off));
    if (lane == 0) red[0][w][h] = v;
  }
  __syncthreads();
  #pragma unroll
  for (int h = 0; h < 8; ++h)
    mx[h] = fmaxf(fmaxf(red[0][0][h], red[0][1][h]), fmaxf(red[0][2][h], red[0][3][h]));
  #pragma unroll
  for (int j = 0; j < 4; ++j)
    #pragma unroll
    for (int h = 0; h < 8; ++h)
      l[j][h] = __expf(l[j][h] - mx[h]);
  #pragma unroll
  for (int h = 0; h < 8; ++h) {
    float v = l[0][h] + l[1][h] + l[2][h] + l[3][h];
    #pragma unroll
    for (int off = 32; off; off >>= 1) v += __shfl_xor(v, off);
    if (lane == 0) red[1][w][h] = v;
  }
  __syncthreads();
  #pragma unroll
  for (int h = 0; h < 8; ++h)
    sm[h] = 1.0f / (red[1][0][h] + red[1][1][h] + red[1][2][h] + red[1][3][h]);
  #pragma unroll
  for (int h = 0; h < 8; ++h) {
    size_t base = ((size_t)(b * 8 + h) * 1024 + n) * 1024;
    #pragma unroll
    for (int j = 0; j < 4; ++j)
      attn[base + t + 256 * j] = f2b(l[j][h] * sm[h]);
  }
}

// ---------------- residual + layernorm (D=256, one block per row) ----------------
__global__ void k_ln(const float* __restrict__ a, const float* __restrict__ bb,
                     const float* __restrict__ g, const float* __restrict__ be,
                     float* __restrict__ of, ushort* __restrict__ ob) {
  int r = blockIdx.x, i = threadIdx.x;
  float t = a[(size_t)r * 256 + i] + bb[(size_t)r * 256 + i];
  __shared__ float red[4];

  float s = t;
  for (int off = 32; off; off >>= 1) s += __shfl_xor(s, off);
  if ((i & 63) == 0) red[i >> 6] = s;
  __syncthreads();
  float mean = (red[0] + red[1] + red[2] + red[3]) * (1.0f / 256.0f);
  __syncthreads();

  float d = t - mean;
  float q = d * d;
  for (int off = 32; off; off >>= 1) q += __shfl_xor(q, off);
  if ((i & 63) == 0) red[i >> 6] = q;
  __syncthreads();
  float var = (red[0] + red[1] + red[2] + red[3]) * (1.0f / 256.0f);

  float y = d * rsqrtf(var + 1e-6f) * g[i] + be[i];
  of[(size_t)r * 256 + i] = y;
  if (ob) ob[(size_t)r * 256 + i] = f2b(y);
}

// ---------------- launch ----------------

extern "C" void kernel_launch(void* const* d_in, const int* in_sizes, int n_in,
                              void* d_out, int out_size, void* d_ws, size_t ws_size,
                              hipStream_t stream) {
  (void)in_sizes; (void)n_in; (void)out_size; (void)ws_size;
  const float* node = (const float*)d_in[0];
  const float* edge = (const float*)d_in[1];
  const float* Wq   = (const float*)d_in[2];
  const float* Wk   = (const float*)d_in[3];
  const float* Wv   = (const float*)d_in[4];
  const float* Wp   = (const float*)d_in[5];
  const float* bp   = (const float*)d_in[6];
  const float* g1   = (const float*)d_in[7];
  const float* be1  = (const float*)d_in[8];
  const float* W1   = (const float*)d_in[9];
  const float* b1   = (const float*)d_in[10];
  const float* W2   = (const float*)d_in[11];
  const float* b2   = (const float*)d_in[12];
  const float* g2   = (const float*)d_in[13];
  const float* be2  = (const float*)d_in[14];
  float* out = (float*)d_out;

  char* ws = (char*)d_ws;
  size_t off = 0;
  auto alloc = [&](size_t bytes) -> char* {
    char* p = ws + off;
    off = (off + bytes + 255) & ~(size_t)255;
    return p;
  };
  ushort* node_bf = (ushort*)alloc((size_t)R_ * D_ * 2);
  ushort* wqkvT   = (ushort*)alloc((size_t)1536 * 256 * 2);
  ushort* wkeT    = (ushort*)alloc((size_t)512 * 512 * 2);
  ushort* wpT     = (ushort*)alloc((size_t)256 * 512 * 2);
  ushort* w1T     = (ushort*)alloc((size_t)1024 * 256 * 2);
  ushort* w2T     = (ushort*)alloc((size_t)256 * 1024 * 2);
  ushort* qkv     = (ushort*)alloc((size_t)R_ * 1536 * 2);        // 6 MiB
  float*  qe      = (float*) alloc((size_t)R_ * 512 * 4);         // 4 MiB
  ushort* vt      = (ushort*)alloc((size_t)16 * 64 * 1024 * 2);   // 2 MiB
  __half* logits  = (__half*)alloc((size_t)16 * 1024 * 1024 * 2); // 32 MiB fp16
  ushort* attn    = (ushort*)alloc((size_t)16 * 1024 * 1024 * 2); // 32 MiB
  ushort* mo      = (ushort*)alloc((size_t)R_ * 512 * 2);
  float*  mha     = (float*) alloc((size_t)R_ * 256 * 4);
  float*  xf      = (float*) alloc((size_t)R_ * 256 * 4);
  ushort* xb      = (ushort*)alloc((size_t)R_ * 256 * 2);
  ushort* hb      = (ushort*)alloc((size_t)R_ * 1024 * 2);
  float*  ff      = (float*) alloc((size_t)R_ * 256 * 4);

  // --- single fused pack ---
  k_pack<<<dim3(7168), dim3(256), 0, stream>>>(node, Wq, Wk, Wv, Wp, W1, W2,
                                               node_bf, wqkvT, wkeT, wpT, w1T, w2T);

  // --- qkv = node @ Wqkv (bf16 out, q pre-scaled) ---
  k_gemm<0, 1, 1, false><<<dim3(32, 24, 1), dim3(256), 0, stream>>>(
      node_bf, wqkvT, qkv, nullptr, 2048, 1536, 256, 256, 256, 1536,
      0LL, 0LL, 0LL, 0LL, 0LL, 0LL);

  // --- qe = q @ blockdiag(WkE^T)  (fp32 out; BDIAG skips the zero K-blocks) ---
  k_gemm<0, 0, 1, true><<<dim3(32, 8, 1), dim3(256), 0, stream>>>(
      qkv, wkeT, qe, nullptr, 2048, 512, 512, 1536, 512, 512,
      0LL, 0LL, 0LL, 0LL, 0LL, 0LL);

  // --- vT pack (for attn@v B-panel) ---
  k_vT<<<dim3(4096), dim3(256), 0, stream>>>(qkv, vt);

  // --- node logits = q @ kn^T  (batched over (b,h); 64x256 tiles; fp16 out) ---
  k_gemm<0, 2, 4, false><<<dim3(16, 4, 16), dim3(256), 0, stream>>>(
      qkv, qkv + 512, logits, nullptr, 1024, 1024, 64, 1536, 1536, 1024,
      1572864LL, 64LL, 1572864LL, 64LL, 8388608LL, 1048576LL);

  // --- fused: edge MFMA dot + node logits + softmax -> bf16 attn ---
  k_fused<<<dim3(2048), dim3(256), 0, stream>>>(edge, qe, logits, attn);

  // --- mo = attn @ v  (batched; Bt = vT; bf16 out as [b][n][h*64+o]) ---
  k_gemm<0, 1, 1, false><<<dim3(16, 1, 16), dim3(256), 0, stream>>>(
      attn, vt, mo, nullptr, 1024, 64, 1024, 1024, 1024, 512,
      8388608LL, 1048576LL, 524288LL, 65536LL, 524288LL, 64LL);

  // --- mha = mo @ Wp + bp  (fp32) ---
  k_gemm<2, 0, 1, false><<<dim3(32, 4, 1), dim3(256), 0, stream>>>(
      mo, wpT, mha, bp, 2048, 256, 512, 512, 512, 256,
      0LL, 0LL, 0LL, 0LL, 0LL, 0LL);

  // --- x = LN1(node + mha) -> xf (fp32), xb (bf16) ---
  k_ln<<<dim3(2048), dim3(256), 0, stream>>>(node, mha, g1, be1, xf, xb);

  // --- ffn hidden = relu(x @ W1 + b1)  (bf16) ---
  k_gemm<3, 1, 1, false><<<dim3(32, 16, 1), dim3(256), 0, stream>>>(
      xb, w1T, hb, b1, 2048, 1024, 256, 256, 256, 1024,
      0LL, 0LL, 0LL, 0LL, 0LL, 0LL);

  // --- ff = hidden @ W2 + b2  (fp32) ---
  k_gemm<2, 0, 1, false><<<dim3(32, 4, 1), dim3(256), 0, stream>>>(
      hb, w2T, ff, b2, 2048, 256, 1024, 1024, 1024, 256,
      0LL, 0LL, 0LL, 0LL, 0LL, 0LL);

  // --- out = LN2(x + ff)  (fp32 to d_out) ---
  k_ln<<<dim3(2048), dim3(256), 0, stream>>>(xf, ff, g2, be2, out, nullptr);
}

// Round 9
// 226.701 us; speedup vs baseline: 1.1914x; 1.0004x over previous
//
#include <hip/hip_runtime.h>
#include <hip/hip_bf16.h>
#include <hip/hip_fp16.h>

// Problem constants
#define B_  2
#define N_  1024
#define D_  256
#define E_  64
#define H_  8
#define HS_ 64
#define FF_ 1024
#define R_  (B_*N_)   // 2048 rows (b,n)

typedef short bf8 __attribute__((ext_vector_type(8)));   // 8 bf16 (bit pattern) = 4 VGPRs
typedef float f4  __attribute__((ext_vector_type(4)));

static __device__ __forceinline__ ushort f2b(float f) {
  __hip_bfloat16 h = __float2bfloat16(f);
  return *reinterpret_cast<ushort*>(&h);
}

static __device__ __forceinline__ ushort f2h(float f) {
  __half h = __float2half(f);
  return *reinterpret_cast<ushort*>(&h);
}

static __device__ __forceinline__ float h2f(ushort u) {
  __half h = *reinterpret_cast<__half*>(&u);
  return __half2float(h);
}

static __device__ __forceinline__ ushort4 f4_to_b4(float4 v) {
  ushort4 r;
  r.x = f2b(v.x); r.y = f2b(v.y); r.z = f2b(v.z); r.w = f2b(v.w);
  return r;
}

// ---------------- fused weight pack (all bf16, B-matrices TRANSPOSED [N][K]) ----------------
__global__ void k_pack(const float* __restrict__ node, const float* __restrict__ Wq,
                       const float* __restrict__ Wk, const float* __restrict__ Wv,
                       const float* __restrict__ Wp, const float* __restrict__ W1,
                       const float* __restrict__ W2,
                       ushort* __restrict__ node_bf, ushort* __restrict__ wqkvT,
                       ushort* __restrict__ wkeT, ushort* __restrict__ wpT,
                       ushort* __restrict__ w1T, ushort* __restrict__ w2T) {
  int idx = blockIdx.x * 256 + threadIdx.x;
  if (idx < 524288) {                       // node -> bf16
    node_bf[idx] = f2b(node[idx]);
    return;
  }
  idx -= 524288;
  if (idx < 393216) {                       // wqkvT[c][i], c in [0,1536), K=256
    int c = idx >> 8, i = idx & 255;
    int mat = c >> 9, h = (c >> 6) & 7, o = c & 63;
    float v;
    if (mat == 0)      v = Wq[(h * 256 + i) * 64 + o] * 0.125f;   // q scaled 1/sqrt(HS)
    else if (mat == 1) v = Wk[(h * 320 + i) * 64 + o];            // Wk: [H][320][64]
    else               v = Wv[(h * 256 + i) * 64 + o];
    wqkvT[idx] = f2b(v);
    return;
  }
  idx -= 393216;
  if (idx < 262144) {                       // wkeT[c=h2*64+e][r=h*64+o]  (block-diagonal)
    int c = idx >> 9, r = idx & 511;
    int h2 = c >> 6, e = c & 63, h = r >> 6, o = r & 63;
    wkeT[idx] = (h2 == h) ? f2b(Wk[(h * 320 + 256 + e) * 64 + o]) : (ushort)0;
    return;
  }
  idx -= 262144;
  if (idx < 131072) {                       // wpT[c][r], c in [0,256), r = h*64+i
    int c = idx >> 9, r = idx & 511;
    wpT[idx] = f2b(Wp[r * 256 + c]);
    return;
  }
  idx -= 131072;
  if (idx < 262144) {                       // w1T[c][k], c in [0,1024), K=256
    int c = idx >> 8, k = idx & 255;
    w1T[idx] = f2b(W1[k * 1024 + c]);
    return;
  }
  idx -= 262144;
  {                                         // w2T[c][k], c in [0,256), K=1024
    int c = idx >> 10, k = idx & 1023;
    w2T[idx] = f2b(W2[k * 256 + c]);
  }
}

// vT[b][h][o][m] <- qkv[(b*1024+m)*1536 + 1024 + h*64 + o]   (B^T panel for attn@v)
__global__ void k_vT(const ushort* __restrict__ qkv, ushort* __restrict__ vt) {
  int idx = blockIdx.x * 256 + threadIdx.x;   // 16*64*1024
  if (idx >= 16 * 64 * 1024) return;
  int m = idx & 1023;
  int rest = idx >> 10;
  int o = rest & 63;
  int bh = rest >> 6;
  int b = bh >> 3, h = bh & 7;
  vt[idx] = qkv[(size_t)(b * 1024 + m) * 1536 + 1024 + h * 64 + o];
}

// ---------------- generic bf16 MFMA GEMM, B pre-transposed ----------------
// C[M x N] = A[M x K] @ B[K x N];  Bt is B^T, row-major [N][K] with stride ldbt.
// EPI: 0=none, 2=+bias, 3=+bias,relu   OFMT: 0=f32, 1=bf16, 2=f16
// NBT: 64-col tiles per block (block = 64 x 64*NBT)
// BDIAG: B block-diagonal with 64x64 blocks -> K-loop restricted to [c0, c0+64)
// Batched via blockIdx.z: offset = (z>>3)*s1 + (z&7)*s2  (element offsets)
template<int EPI, int OFMT, int NBT, bool BDIAG>
__global__ void k_gemm(const ushort* __restrict__ A, const ushort* __restrict__ Bt,
                       void* __restrict__ Cv, const float* __restrict__ bias,
                       int M, int N, int K, int lda, int ldbt, int ldc,
                       long long as1, long long as2, long long bs1, long long bs2,
                       long long cs1, long long cs2) {
  int z = blockIdx.z;
  const ushort* Ab = A  + (size_t)((z >> 3) * as1 + (z & 7) * as2);
  const ushort* Bb = Bt + (size_t)((z >> 3) * bs1 + (z & 7) * bs2);
  size_t coff = (size_t)((z >> 3) * cs1 + (z & 7) * cs2);
  int r0 = blockIdx.x * 64, c0 = blockIdx.y * (64 * NBT);

  __shared__ ushort As[64][40];          // [row][k], +8 pad
  __shared__ ushort Bs[64 * NBT][40];    // [col][k], +8 pad

  int tid = threadIdx.x;
  int lane = tid & 63, w = tid >> 6;
  int wm = w >> 1, wn = w & 1;            // wave -> 32-row half x 32-col half
  int kg = lane >> 4, lr = lane & 15;

  f4 acc[2][2 * NBT] = {};

  int kbeg = BDIAG ? c0 : 0;
  int kend = BDIAG ? c0 + 64 : K;
  for (int k0 = kbeg; k0 < kend; k0 += 32) {
    __syncthreads();
    { // stage A tile 64x32 (one 16B load per thread)
      int row = tid >> 2, ch = tid & 3;
      *(int4*)&As[row][ch * 8] = *(const int4*)(Ab + (size_t)(r0 + row) * lda + k0 + ch * 8);
    }
    #pragma unroll
    for (int i = 0; i < NBT; ++i) { // stage Bt tile 64*NBT x 32
      int row = (tid >> 2) + 64 * i, ch = tid & 3;
      *(int4*)&Bs[row][ch * 8] = *(const int4*)(Bb + (size_t)(c0 + row) * ldbt + k0 + ch * 8);
    }
    __syncthreads();

    bf8 bfr[2 * NBT];
    #pragma unroll
    for (int nt = 0; nt < NBT; ++nt)
      #pragma unroll
      for (int cb = 0; cb < 2; ++cb)
        bfr[nt * 2 + cb] = *(const bf8*)&Bs[nt * 64 + wn * 32 + cb * 16 + lr][kg * 8];
    #pragma unroll
    for (int rb = 0; rb < 2; ++rb) {
      bf8 af = *(const bf8*)&As[wm * 32 + rb * 16 + lr][kg * 8];     // A: row=l&15, k=8*kg+j
      #pragma unroll
      for (int q = 0; q < 2 * NBT; ++q)
        acc[rb][q] = __builtin_amdgcn_mfma_f32_16x16x32_bf16(af, bfr[q], acc[rb][q], 0, 0, 0);
    }
  }

  float*  Cf = (float*)Cv;
  ushort* Cb = (ushort*)Cv;
  __half* Ch = (__half*)Cv;
  #pragma unroll
  for (int rb = 0; rb < 2; ++rb) {
    #pragma unroll
    for (int q = 0; q < 2 * NBT; ++q) {
      #pragma unroll
      for (int rr = 0; rr < 4; ++rr) {
        int row = r0 + wm * 32 + rb * 16 + kg * 4 + rr;   // D: col=l&15, row=4*kg+reg
        int col = c0 + (q >> 1) * 64 + wn * 32 + (q & 1) * 16 + lr;
        size_t ci = coff + (size_t)row * ldc + col;
        float v = acc[rb][q][rr];
        if (EPI >= 2) v += bias[col];
        if (EPI == 3) v = fmaxf(v, 0.0f);
        if (OFMT == 1)      Cb[ci] = f2b(v);
        else if (OFMT == 2) Ch[ci] = __float2half(v);
        else                Cf[ci] = v;
      }
    }
  }
}

// ---------------- fused edge-logits (MFMA) + node-logits + softmax -> bf16 attn ----------------
// lg layout [h][1032] fp16: MFMA epilogue packs 4 m's into one ds_write_b64;
// softmax ownership m = 4t+j -> ushort4 logN loads / attn stores / lg reads.
__global__ __launch_bounds__(256, 4) void k_fused(
    const float* __restrict__ edge, const float* __restrict__ qe,
    const __half* __restrict__ logN, ushort* __restrict__ attn) {
  int bid = blockIdx.x;            // b*1024 + n
  int b = bid >> 10, n = bid & 1023;
  int t = threadIdx.x;
  int lane = t & 63, w = t >> 6;
  int kg = lane >> 4, lr = lane & 15;

  __shared__ ushort As[128 * 64];  // 16 KB bf16 stage, slot^(row&7) swizzle
  __shared__ ushort lg[8][1032];   // block logits [h][m] fp16, +8 pad (16.5 KB)
  __shared__ float red[2][4][8];

  // ---- B fragments (qe row -> bf16), built once, kept in 8 VGPRs ----
  bf8 bq[2];
  {
    const float* qrow = qe + (size_t)bid * 512 + (size_t)(lr & 7) * 64;
    #pragma unroll
    for (int kk = 0; kk < 2; ++kk) {
      float4 a  = *reinterpret_cast<const float4*>(&qrow[kk * 32 + kg * 8]);
      float4 c4 = *reinterpret_cast<const float4*>(&qrow[kk * 32 + kg * 8 + 4]);
      bq[kk][0] = (short)f2b(a.x);  bq[kk][1] = (short)f2b(a.y);
      bq[kk][2] = (short)f2b(a.z);  bq[kk][3] = (short)f2b(a.w);
      bq[kk][4] = (short)f2b(c4.x); bq[kk][5] = (short)f2b(c4.y);
      bq[kk][6] = (short)f2b(c4.z); bq[kk][7] = (short)f2b(c4.w);
    }
  }

  const float* eb = edge + (size_t)bid * 65536;   // 1024 rows x 64 floats

  // prefetch tile 0 (8 float4/thread, fully coalesced)
  float4 pf[8];
  #pragma unroll
  for (int u = 0; u < 8; ++u)
    pf[u] = reinterpret_cast<const float4*>(eb)[t + 256 * u];

  #pragma unroll 1
  for (int tl = 0; tl < 8; ++tl) {
    __syncthreads();               // prev tile's A-frag reads done
    #pragma unroll
    for (int u = 0; u < 8; ++u) {  // cvt fp32->bf16, swizzled write: slot ^= row&7
      int g = t + 256 * u;
      int rl = g >> 4, c = t & 15;          // row 0..127, float4-slot 0..15
      int slot = (c >> 1) ^ (rl & 7), half = c & 1;
      *reinterpret_cast<ushort4*>(&As[rl * 64 + slot * 8 + half * 4]) = f4_to_b4(pf[u]);
    }
    if (tl < 7) {                  // issue next tile's loads; hide under compute
      const float4* src = reinterpret_cast<const float4*>(eb + (tl + 1) * 8192);
      #pragma unroll
      for (int u = 0; u < 8; ++u) pf[u] = src[t + 256 * u];
    }
    __syncthreads();               // stage visible

    // wave w owns stage rows [w*32, w*32+32): 2 sub-tiles of 16 m
    #pragma unroll
    for (int sub = 0; sub < 2; ++sub) {
      int sr = w * 32 + sub * 16 + lr;      // A row in stage
      f4 acc = {};
      #pragma unroll
      for (int kk = 0; kk < 2; ++kk) {
        bf8 af = *reinterpret_cast<const bf8*>(&As[sr * 64 + (((kk * 4 + kg) ^ (sr & 7)) << 3)]);
        acc = __builtin_amdgcn_mfma_f32_16x16x32_bf16(af, bq[kk], acc, 0, 0, 0);
      }
      if (lr < 8) {                         // D: col=l&15 (=h), row=4*kg+rr
        int mbase = tl * 128 + w * 32 + sub * 16 + kg * 4;
        uint2 pk;
        pk.x = (uint)f2h(acc[0]) | ((uint)f2h(acc[1]) << 16);
        pk.y = (uint)f2h(acc[2]) | ((uint)f2h(acc[3]) << 16);
        *reinterpret_cast<uint2*>(&lg[lr][mbase]) = pk;   // one 8B write for 4 m's
      }
    }
  }

  // issue node-logit loads BEFORE the barrier (ushort4 = 8B/lane, m = 4t..4t+3)
  ushort4 lNr[8];
  #pragma unroll
  for (int h = 0; h < 8; ++h)
    lNr[h] = *reinterpret_cast<const ushort4*>(
        &reinterpret_cast<const ushort*>(logN)[((size_t)(b * 8 + h) * 1024 + n) * 1024 + 4 * t]);
  __syncthreads();                 // lg complete

  // ---- softmax: thread owns m = 4t + j ----
  float l[4][8];
  #pragma unroll
  for (int h = 0; h < 8; ++h) {
    ushort4 lv = *reinterpret_cast<const ushort4*>(&lg[h][4 * t]);
    l[0][h] = h2f(lv.x) + h2f(lNr[h].x);
    l[1][h] = h2f(lv.y) + h2f(lNr[h].y);
    l[2][h] = h2f(lv.z) + h2f(lNr[h].z);
    l[3][h] = h2f(lv.w) + h2f(lNr[h].w);
  }
  float mx[8], sm[8];
  #pragma unroll
  for (int h = 0; h < 8; ++h) {
    float v = fmaxf(fmaxf(l[0][h], l[1][h]), fmaxf(l[2][h], l[3][h]));
    #pragma unroll
    for (int off = 32; off; off >>= 1) v = fmaxf(v, __shfl_xor(v, off));
    if (lane == 0) red[0][w][h] = v;
  }
  __syncthreads();
  #pragma unroll
  for (int h = 0; h < 8; ++h)
    mx[h] = fmaxf(fmaxf(red[0][0][h], red[0][1][h]), fmaxf(red[0][2][h], red[0][3][h]));
  #pragma unroll
  for (int j = 0; j < 4; ++j)
    #pragma unroll
    for (int h = 0; h < 8; ++h)
      l[j][h] = __expf(l[j][h] - mx[h]);
  #pragma unroll
  for (int h = 0; h < 8; ++h) {
    float v = l[0][h] + l[1][h] + l[2][h] + l[3][h];
    #pragma unroll
    for (int off = 32; off; off >>= 1) v += __shfl_xor(v, off);
    if (lane == 0) red[1][w][h] = v;
  }
  __syncthreads();
  #pragma unroll
  for (int h = 0; h < 8; ++h)
    sm[h] = 1.0f / (red[1][0][h] + red[1][1][h] + red[1][2][h] + red[1][3][h]);
  #pragma unroll
  for (int h = 0; h < 8; ++h) {
    size_t base = ((size_t)(b * 8 + h) * 1024 + n) * 1024;
    ushort4 o;
    o.x = f2b(l[0][h] * sm[h]);
    o.y = f2b(l[1][h] * sm[h]);
    o.z = f2b(l[2][h] * sm[h]);
    o.w = f2b(l[3][h] * sm[h]);
    *reinterpret_cast<ushort4*>(&attn[base + 4 * t]) = o;   // 8B/lane store
  }
}

// ---------------- residual + layernorm (D=256, one block per row) ----------------
__global__ void k_ln(const float* __restrict__ a, const float* __restrict__ bb,
                     const float* __restrict__ g, const float* __restrict__ be,
                     float* __restrict__ of, ushort* __restrict__ ob) {
  int r = blockIdx.x, i = threadIdx.x;
  float t = a[(size_t)r * 256 + i] + bb[(size_t)r * 256 + i];
  __shared__ float red[4];

  float s = t;
  for (int off = 32; off; off >>= 1) s += __shfl_xor(s, off);
  if ((i & 63) == 0) red[i >> 6] = s;
  __syncthreads();
  float mean = (red[0] + red[1] + red[2] + red[3]) * (1.0f / 256.0f);
  __syncthreads();

  float d = t - mean;
  float q = d * d;
  for (int off = 32; off; off >>= 1) q += __shfl_xor(q, off);
  if ((i & 63) == 0) red[i >> 6] = q;
  __syncthreads();
  float var = (red[0] + red[1] + red[2] + red[3]) * (1.0f / 256.0f);

  float y = d * rsqrtf(var + 1e-6f) * g[i] + be[i];
  of[(size_t)r * 256 + i] = y;
  if (ob) ob[(size_t)r * 256 + i] = f2b(y);
}

// ---------------- launch ----------------

extern "C" void kernel_launch(void* const* d_in, const int* in_sizes, int n_in,
                              void* d_out, int out_size, void* d_ws, size_t ws_size,
                              hipStream_t stream) {
  (void)in_sizes; (void)n_in; (void)out_size; (void)ws_size;
  const float* node = (const float*)d_in[0];
  const float* edge = (const float*)d_in[1];
  const float* Wq   = (const float*)d_in[2];
  const float* Wk   = (const float*)d_in[3];
  const float* Wv   = (const float*)d_in[4];
  const float* Wp   = (const float*)d_in[5];
  const float* bp   = (const float*)d_in[6];
  const float* g1   = (const float*)d_in[7];
  const float* be1  = (const float*)d_in[8];
  const float* W1   = (const float*)d_in[9];
  const float* b1   = (const float*)d_in[10];
  const float* W2   = (const float*)d_in[11];
  const float* b2   = (const float*)d_in[12];
  const float* g2   = (const float*)d_in[13];
  const float* be2  = (const float*)d_in[14];
  float* out = (float*)d_out;

  char* ws = (char*)d_ws;
  size_t off = 0;
  auto alloc = [&](size_t bytes) -> char* {
    char* p = ws + off;
    off = (off + bytes + 255) & ~(size_t)255;
    return p;
  };
  ushort* node_bf = (ushort*)alloc((size_t)R_ * D_ * 2);
  ushort* wqkvT   = (ushort*)alloc((size_t)1536 * 256 * 2);
  ushort* wkeT    = (ushort*)alloc((size_t)512 * 512 * 2);
  ushort* wpT     = (ushort*)alloc((size_t)256 * 512 * 2);
  ushort* w1T     = (ushort*)alloc((size_t)1024 * 256 * 2);
  ushort* w2T     = (ushort*)alloc((size_t)256 * 1024 * 2);
  ushort* qkv     = (ushort*)alloc((size_t)R_ * 1536 * 2);        // 6 MiB
  float*  qe      = (float*) alloc((size_t)R_ * 512 * 4);         // 4 MiB
  ushort* vt      = (ushort*)alloc((size_t)16 * 64 * 1024 * 2);   // 2 MiB
  __half* logits  = (__half*)alloc((size_t)16 * 1024 * 1024 * 2); // 32 MiB fp16
  ushort* attn    = (ushort*)alloc((size_t)16 * 1024 * 1024 * 2); // 32 MiB
  ushort* mo      = (ushort*)alloc((size_t)R_ * 512 * 2);
  float*  mha     = (float*) alloc((size_t)R_ * 256 * 4);
  float*  xf      = (float*) alloc((size_t)R_ * 256 * 4);
  ushort* xb      = (ushort*)alloc((size_t)R_ * 256 * 2);
  ushort* hb      = (ushort*)alloc((size_t)R_ * 1024 * 2);
  float*  ff      = (float*) alloc((size_t)R_ * 256 * 4);

  // --- single fused pack ---
  k_pack<<<dim3(7168), dim3(256), 0, stream>>>(node, Wq, Wk, Wv, Wp, W1, W2,
                                               node_bf, wqkvT, wkeT, wpT, w1T, w2T);

  // --- qkv = node @ Wqkv (bf16 out, q pre-scaled) ---
  k_gemm<0, 1, 1, false><<<dim3(32, 24, 1), dim3(256), 0, stream>>>(
      node_bf, wqkvT, qkv, nullptr, 2048, 1536, 256, 256, 256, 1536,
      0LL, 0LL, 0LL, 0LL, 0LL, 0LL);

  // --- qe = q @ blockdiag(WkE^T)  (fp32 out; BDIAG skips the zero K-blocks) ---
  k_gemm<0, 0, 1, true><<<dim3(32, 8, 1), dim3(256), 0, stream>>>(
      qkv, wkeT, qe, nullptr, 2048, 512, 512, 1536, 512, 512,
      0LL, 0LL, 0LL, 0LL, 0LL, 0LL);

  // --- vT pack (for attn@v B-panel) ---
  k_vT<<<dim3(4096), dim3(256), 0, stream>>>(qkv, vt);

  // --- node logits = q @ kn^T  (batched over (b,h); 64x256 tiles; fp16 out) ---
  k_gemm<0, 2, 4, false><<<dim3(16, 4, 16), dim3(256), 0, stream>>>(
      qkv, qkv + 512, logits, nullptr, 1024, 1024, 64, 1536, 1536, 1024,
      1572864LL, 64LL, 1572864LL, 64LL, 8388608LL, 1048576LL);

  // --- fused: edge MFMA dot + node logits + softmax -> bf16 attn ---
  k_fused<<<dim3(2048), dim3(256), 0, stream>>>(edge, qe, logits, attn);

  // --- mo = attn @ v  (batched; Bt = vT; bf16 out as [b][n][h*64+o]) ---
  k_gemm<0, 1, 1, false><<<dim3(16, 1, 16), dim3(256), 0, stream>>>(
      attn, vt, mo, nullptr, 1024, 64, 1024, 1024, 1024, 512,
      8388608LL, 1048576LL, 524288LL, 65536LL, 524288LL, 64LL);

  // --- mha = mo @ Wp + bp  (fp32) ---
  k_gemm<2, 0, 1, false><<<dim3(32, 4, 1), dim3(256), 0, stream>>>(
      mo, wpT, mha, bp, 2048, 256, 512, 512, 512, 256,
      0LL, 0LL, 0LL, 0LL, 0LL, 0LL);

  // --- x = LN1(node + mha) -> xf (fp32), xb (bf16) ---
  k_ln<<<dim3(2048), dim3(256), 0, stream>>>(node, mha, g1, be1, xf, xb);

  // --- ffn hidden = relu(x @ W1 + b1)  (bf16) ---
  k_gemm<3, 1, 1, false><<<dim3(32, 16, 1), dim3(256), 0, stream>>>(
      xb, w1T, hb, b1, 2048, 1024, 256, 256, 256, 1024,
      0LL, 0LL, 0LL, 0LL, 0LL, 0LL);

  // --- ff = hidden @ W2 + b2  (fp32) ---
  k_gemm<2, 0, 1, false><<<dim3(32, 4, 1), dim3(256), 0, stream>>>(
      hb, w2T, ff, b2, 2048, 256, 1024, 1024, 1024, 256,
      0LL, 0LL, 0LL, 0LL, 0LL, 0LL);

  // --- out = LN2(x + ff)  (fp32 to d_out) ---
  k_ln<<<dim3(2048), dim3(256), 0, stream>>>(xf, ff, g2, be2, out, nullptr);
}